// Round 1
// baseline (853.391 us; speedup 1.0000x reference)
//
#include <hip/hip_runtime.h>

typedef __bf16 bf16_t;
typedef __bf16 bf16x4 __attribute__((ext_vector_type(4)));
typedef __bf16 bf16x8 __attribute__((ext_vector_type(8)));
typedef float f32x4 __attribute__((ext_vector_type(4)));

#define QKV_SEG 33554432L  // elements per q/k/v segment: 2048 win * 8 heads * 64 tok * 32 d

// ---------------- weight fp32 -> bf16 convert ----------------
__global__ __launch_bounds__(256) void cvt_kernel(const float* __restrict__ src,
                                                  bf16_t* __restrict__ dst) {
  int i = (blockIdx.x * 256 + threadIdx.x) * 4;
  float4 v = *(const float4*)(src + i);
  bf16x4 o;
  o[0] = (bf16_t)v.x; o[1] = (bf16_t)v.y; o[2] = (bf16_t)v.z; o[3] = (bf16_t)v.w;
  *(bf16x4*)(dst + i) = o;
}

// ---------------- LayerNorm (+ optional shift/window-partition gather) ----------------
// one wave per token (256 ch, 4/lane); 4 tokens per block
__global__ __launch_bounds__(256) void ln_kernel(const float* __restrict__ src,
                                                 const float* __restrict__ gw,
                                                 const float* __restrict__ gb,
                                                 bf16_t* __restrict__ dst,
                                                 int shifted) {
  int lane = threadIdx.x & 63, wv = threadIdx.x >> 6;
  long m = (long)blockIdx.x * 4 + wv;  // dest row (window-token order if shifted)
  long srow;
  if (shifted) {
    long b_ = m >> 6; int tok = (int)(m & 63);
    int bb = (int)(b_ >> 8), win = (int)(b_ & 255);
    int wh = win >> 4, ww = win & 15;
    int ii = tok >> 3, jj = tok & 7;
    int hh = (wh * 8 + ii + 4) & 127, wp = (ww * 8 + jj + 4) & 127;
    srow = ((long)bb << 14) + (hh << 7) + wp;
  } else {
    srow = m;
  }
  float4 v = *(const float4*)(src + srow * 256 + lane * 4);
  float s = v.x + v.y + v.z + v.w;
  float s2 = v.x * v.x + v.y * v.y + v.z * v.z + v.w * v.w;
#pragma unroll
  for (int msk = 1; msk < 64; msk <<= 1) {
    s += __shfl_xor(s, msk);
    s2 += __shfl_xor(s2, msk);
  }
  float mean = s * (1.f / 256.f);
  float var = s2 * (1.f / 256.f) - mean * mean;
  float rs = rsqrtf(var + 1e-5f);
  float4 g4 = *(const float4*)(gw + lane * 4);
  float4 b4 = *(const float4*)(gb + lane * 4);
  bf16x4 o;
  o[0] = (bf16_t)((v.x - mean) * rs * g4.x + b4.x);
  o[1] = (bf16_t)((v.y - mean) * rs * g4.y + b4.y);
  o[2] = (bf16_t)((v.z - mean) * rs * g4.z + b4.z);
  o[3] = (bf16_t)((v.w - mean) * rs * g4.w + b4.w);
  *(bf16x4*)(dst + m * 256 + lane * 4) = o;
}

// ---------------- GEMM: C[M,N] = A[M,K] @ Bw[N,K]^T + bias, epilogue variants ----------------
// EPI 0: qkv scatter (q/k/v_t layouts)   out_bf = qkv base
// EPI 1: proj + reverse-shift residual   out_f[dst] = val + resid[dst]
// EPI 2: exact gelu -> bf16 [m][1024]
// EPI 3: + resid[m*256+n] -> fp32 out
template <int EPI>
__global__ __launch_bounds__(256) void gemm_kernel(const bf16_t* __restrict__ A,
                                                   const bf16_t* __restrict__ Bw,
                                                   const float* __restrict__ bias, int K,
                                                   bf16_t* __restrict__ out_bf, float* out_f,
                                                   const float* resid) {
  __shared__ bf16_t As[128][40];  // +8 pad: 80B row stride -> 2-way bank alias (free)
  __shared__ bf16_t Bs[128][40];
  int tid = threadIdx.x;
  int lane = tid & 63, wv = tid >> 6;
  int wm = wv >> 1, wn = wv & 1;
  long m0 = (long)blockIdx.y * 128;
  int n0 = blockIdx.x * 128;
  int srow = tid >> 2, sslot = tid & 3;
  int lr = lane & 15, lk = (lane >> 4) * 8, g = lane >> 4;
  f32x4 acc[4][4] = {};

  for (int k0 = 0; k0 < K; k0 += 32) {
    bf16x8 a0 = *(const bf16x8*)(A + (m0 + srow) * K + k0 + sslot * 8);
    bf16x8 a1 = *(const bf16x8*)(A + (m0 + srow + 64) * K + k0 + sslot * 8);
    bf16x8 b0 = *(const bf16x8*)(Bw + (long)(n0 + srow) * K + k0 + sslot * 8);
    bf16x8 b1 = *(const bf16x8*)(Bw + (long)(n0 + srow + 64) * K + k0 + sslot * 8);
    *(bf16x8*)(&As[srow][sslot * 8]) = a0;
    *(bf16x8*)(&As[srow + 64][sslot * 8]) = a1;
    *(bf16x8*)(&Bs[srow][sslot * 8]) = b0;
    *(bf16x8*)(&Bs[srow + 64][sslot * 8]) = b1;
    __syncthreads();
    bf16x8 af[4], bfr[4];
#pragma unroll
    for (int mf = 0; mf < 4; ++mf) af[mf] = *(const bf16x8*)(&As[wm * 64 + mf * 16 + lr][lk]);
#pragma unroll
    for (int nf = 0; nf < 4; ++nf) bfr[nf] = *(const bf16x8*)(&Bs[wn * 64 + nf * 16 + lr][lk]);
#pragma unroll
    for (int mf = 0; mf < 4; ++mf)
#pragma unroll
      for (int nf = 0; nf < 4; ++nf)
        acc[mf][nf] = __builtin_amdgcn_mfma_f32_16x16x32_bf16(af[mf], bfr[nf], acc[mf][nf], 0, 0, 0);
    __syncthreads();
  }

#pragma unroll
  for (int mf = 0; mf < 4; ++mf) {
#pragma unroll
    for (int nf = 0; nf < 4; ++nf) {
#pragma unroll
      for (int r = 0; r < 4; ++r) {
        long m = m0 + wm * 64 + mf * 16 + 4 * g + r;
        int n = n0 + wn * 64 + nf * 16 + lr;
        float val = acc[mf][nf][r] + bias[n];
        if (EPI == 0) {
          long b_ = m >> 6; int tok = (int)(m & 63);
          int which = n >> 8, rem = n & 255, head = rem >> 5, d = rem & 31;
          long off;
          if (which == 2) off = ((b_ * 8 + head) * 32 + d) * 64 + tok;   // v transposed [d][tok]
          else            off = ((b_ * 8 + head) * 64 + tok) * 32 + d;   // q,k [tok][d]
          out_bf[(long)which * QKV_SEG + off] = (bf16_t)val;
        } else if (EPI == 1) {
          long b_ = m >> 6; int tok = (int)(m & 63);
          int bb = (int)(b_ >> 8), win = (int)(b_ & 255);
          int wh = win >> 4, ww = win & 15;
          int ii = tok >> 3, jj = tok & 7;
          int hh = (wh * 8 + ii + 4) & 127, wp = (ww * 8 + jj + 4) & 127;
          long dst = (((long)bb << 14) + (hh << 7) + wp) * 256 + n;
          out_f[dst] = val + resid[dst];
        } else if (EPI == 2) {
          float t = 0.5f * val * (1.0f + erff(val * 0.70710678118654752f));
          out_bf[m * 1024 + n] = (bf16_t)t;
        } else {
          out_f[m * 256 + n] = val + resid[m * 256 + n];
        }
      }
    }
  }
}

// ---------------- per-window attention: 4 waves x 2 heads ----------------
__global__ __launch_bounds__(256) void attn_kernel(const bf16_t* __restrict__ qkv,
                                                   const float* __restrict__ rpb,
                                                   bf16_t* __restrict__ attn_out) {
  __shared__ float rpb_s[1800];       // 225 x 8
  __shared__ bf16_t P[4][64][72];     // +8 pad: 144B stride -> 2-way
  int tid = threadIdx.x, lane = tid & 63, wv = tid >> 6;
  long b_ = blockIdx.x;
  for (int i = tid; i < 1800; i += 256) rpb_s[i] = rpb[i];
  __syncthreads();
  const bf16_t* q = qkv;
  const bf16_t* k = qkv + QKV_SEG;
  const bf16_t* vt = qkv + 2 * QKV_SEG;
  int lr = lane & 15, lk = (lane >> 4) * 8, g = lane >> 4;
  const float scale = 0.17677669529663688f;  // 32^-0.5

  for (int hh = 0; hh < 2; ++hh) {
    int head = wv * 2 + hh;
    long base = (b_ * 8 + head) * 2048;
    bf16x8 af[4], bfr[4];
#pragma unroll
    for (int mf = 0; mf < 4; ++mf)
      af[mf] = *(const bf16x8*)(q + base + (mf * 16 + lr) * 32 + lk);
#pragma unroll
    for (int nf = 0; nf < 4; ++nf)
      bfr[nf] = *(const bf16x8*)(k + base + (nf * 16 + lr) * 32 + lk);
    f32x4 S[4][4] = {};
#pragma unroll
    for (int mf = 0; mf < 4; ++mf)
#pragma unroll
      for (int nf = 0; nf < 4; ++nf)
        S[mf][nf] = __builtin_amdgcn_mfma_f32_16x16x32_bf16(af[mf], bfr[nf], S[mf][nf], 0, 0, 0);
    // scale + relative position bias
#pragma unroll
    for (int mf = 0; mf < 4; ++mf)
#pragma unroll
      for (int nf = 0; nf < 4; ++nf)
#pragma unroll
        for (int r = 0; r < 4; ++r) {
          int i = mf * 16 + 4 * g + r, j = nf * 16 + lr;
          int rel = ((i >> 3) - (j >> 3) + 7) * 15 + ((i & 7) - (j & 7) + 7);
          S[mf][nf][r] = S[mf][nf][r] * scale + rpb_s[rel * 8 + head];
        }
    // softmax over rows (16-lane groups hold a row's 64 cols as 4 frags x 16 lanes)
#pragma unroll
    for (int mf = 0; mf < 4; ++mf) {
#pragma unroll
      for (int r = 0; r < 4; ++r) {
        float mx = fmaxf(fmaxf(S[mf][0][r], S[mf][1][r]), fmaxf(S[mf][2][r], S[mf][3][r]));
#pragma unroll
        for (int msk = 1; msk < 16; msk <<= 1) mx = fmaxf(mx, __shfl_xor(mx, msk));
        float sm = 0.f;
#pragma unroll
        for (int nf = 0; nf < 4; ++nf) {
          float e = __expf(S[mf][nf][r] - mx);
          S[mf][nf][r] = e;
          sm += e;
        }
#pragma unroll
        for (int msk = 1; msk < 16; msk <<= 1) sm += __shfl_xor(sm, msk);
        float is = 1.f / sm;
        int i = mf * 16 + 4 * g + r;
#pragma unroll
        for (int nf = 0; nf < 4; ++nf) P[wv][i][nf * 16 + lr] = (bf16_t)(S[mf][nf][r] * is);
      }
    }
    // O = P @ V   (A from LDS P, B from transposed v_t, contiguous)
    f32x4 O[4][2] = {};
#pragma unroll
    for (int ks = 0; ks < 2; ++ks) {
      int j0 = ks * 32;
      bf16x8 pa[4], vb[2];
#pragma unroll
      for (int mf = 0; mf < 4; ++mf) pa[mf] = *(const bf16x8*)(&P[wv][mf * 16 + lr][j0 + lk]);
#pragma unroll
      for (int nf = 0; nf < 2; ++nf)
        vb[nf] = *(const bf16x8*)(vt + base + (nf * 16 + lr) * 64 + j0 + lk);
#pragma unroll
      for (int mf = 0; mf < 4; ++mf)
#pragma unroll
        for (int nf = 0; nf < 2; ++nf)
          O[mf][nf] = __builtin_amdgcn_mfma_f32_16x16x32_bf16(pa[mf], vb[nf], O[mf][nf], 0, 0, 0);
    }
#pragma unroll
    for (int mf = 0; mf < 4; ++mf)
#pragma unroll
      for (int nf = 0; nf < 2; ++nf)
#pragma unroll
        for (int r = 0; r < 4; ++r) {
          int i = mf * 16 + 4 * g + r, d = nf * 16 + lr;
          attn_out[(b_ * 64 + i) * 256 + head * 32 + d] = (bf16_t)O[mf][nf][r];
        }
  }
}

extern "C" void kernel_launch(void* const* d_in, const int* in_sizes, int n_in,
                              void* d_out, int out_size, void* d_ws, size_t ws_size,
                              hipStream_t stream) {
  const float* x = (const float*)d_in[0];
  const float* n1w = (const float*)d_in[1];
  const float* n1b = (const float*)d_in[2];
  const float* qkv_w = (const float*)d_in[3];
  const float* qkv_b = (const float*)d_in[4];
  const float* rpb = (const float*)d_in[5];
  const float* proj_w = (const float*)d_in[6];
  const float* proj_b = (const float*)d_in[7];
  const float* n2w = (const float*)d_in[8];
  const float* n2b = (const float*)d_in[9];
  const float* fc1_w = (const float*)d_in[10];
  const float* fc1_b = (const float*)d_in[11];
  const float* fc2_w = (const float*)d_in[12];
  const float* fc2_b = (const float*)d_in[13];
  float* out = (float*)d_out;

  char* ws = (char*)d_ws;
  bf16_t* bufA = (bf16_t*)ws;                       // qkv (201MB) then h (268MB)
  bf16_t* bufB = (bf16_t*)(ws + 268435456L);        // xw / attn_out / y (67MB)
  bf16_t* wq = (bf16_t*)(ws + 335544320L);          // bf16 weights (1.6MB)
  bf16_t* wp = wq + 196608;
  bf16_t* w1 = wp + 65536;
  bf16_t* w2 = w1 + 262144;

  // weights -> bf16
  cvt_kernel<<<192, 256, 0, stream>>>(qkv_w, wq);
  cvt_kernel<<<64, 256, 0, stream>>>(proj_w, wp);
  cvt_kernel<<<256, 256, 0, stream>>>(fc1_w, w1);
  cvt_kernel<<<256, 256, 0, stream>>>(fc2_w, w2);

  // LN1 + shift + window partition -> xw (bufB)
  ln_kernel<<<32768, 256, 0, stream>>>(x, n1w, n1b, bufB, 1);
  // QKV GEMM -> q/k/v_t (bufA)
  gemm_kernel<0><<<dim3(6, 1024), 256, 0, stream>>>(bufB, wq, qkv_b, 256, bufA, nullptr, nullptr);
  // window attention -> attn_out (bufB)
  attn_kernel<<<2048, 256, 0, stream>>>(bufA, rpb, bufB);
  // proj + reverse shift + residual -> x1 (d_out, fp32)
  gemm_kernel<1><<<dim3(2, 1024), 256, 0, stream>>>(bufB, wp, proj_b, 256, nullptr, out, x);
  // LN2 -> y (bufB)
  ln_kernel<<<32768, 256, 0, stream>>>(out, n2w, n2b, bufB, 0);
  // FC1 + gelu -> h (bufA)
  gemm_kernel<2><<<dim3(8, 1024), 256, 0, stream>>>(bufB, w1, fc1_b, 256, bufA, nullptr, nullptr);
  // FC2 + residual -> out (in-place x1 + y)
  gemm_kernel<3><<<dim3(2, 1024), 256, 0, stream>>>(bufA, w2, fc2_b, 1024, nullptr, out, out);
}

// Round 3
// 794.719 us; speedup vs baseline: 1.0738x; 1.0738x over previous
//
#include <hip/hip_runtime.h>

typedef __bf16 bf16_t;
typedef __bf16 bf16x4 __attribute__((ext_vector_type(4)));
typedef __bf16 bf16x8 __attribute__((ext_vector_type(8)));
typedef float f32x4 __attribute__((ext_vector_type(4)));

#define QKV_SEG 33554432L  // elements per q/k/v segment: 2048 win * 8 heads * 64 tok * 32 d

#define GLDS(gp, lp)                                                                   \
  __builtin_amdgcn_global_load_lds((const __attribute__((address_space(1))) void*)(gp), \
                                   (__attribute__((address_space(3))) void*)(lp), 16, 0, 0)

// ---------------- weight fp32 -> bf16 convert ----------------
__global__ __launch_bounds__(256) void cvt_kernel(const float* __restrict__ src,
                                                  bf16_t* __restrict__ dst) {
  int i = (blockIdx.x * 256 + threadIdx.x) * 4;
  float4 v = *(const float4*)(src + i);
  bf16x4 o;
  o[0] = (bf16_t)v.x; o[1] = (bf16_t)v.y; o[2] = (bf16_t)v.z; o[3] = (bf16_t)v.w;
  *(bf16x4*)(dst + i) = o;
}

// ---------------- LayerNorm (+ optional shift/window-partition gather) ----------------
// one wave per token (256 ch, 4/lane); 4 tokens per block
__global__ __launch_bounds__(256) void ln_kernel(const float* __restrict__ src,
                                                 const float* __restrict__ gw,
                                                 const float* __restrict__ gb,
                                                 bf16_t* __restrict__ dst,
                                                 int shifted) {
  int lane = threadIdx.x & 63, wv = threadIdx.x >> 6;
  long m = (long)blockIdx.x * 4 + wv;  // dest row (window-token order if shifted)
  long srow;
  if (shifted) {
    long b_ = m >> 6; int tok = (int)(m & 63);
    int bb = (int)(b_ >> 8), win = (int)(b_ & 255);
    int wh = win >> 4, ww = win & 15;
    int ii = tok >> 3, jj = tok & 7;
    int hh = (wh * 8 + ii + 4) & 127, wp = (ww * 8 + jj + 4) & 127;
    srow = ((long)bb << 14) + (hh << 7) + wp;
  } else {
    srow = m;
  }
  float4 v = *(const float4*)(src + srow * 256 + lane * 4);
  float s = v.x + v.y + v.z + v.w;
  float s2 = v.x * v.x + v.y * v.y + v.z * v.z + v.w * v.w;
#pragma unroll
  for (int msk = 1; msk < 64; msk <<= 1) {
    s += __shfl_xor(s, msk);
    s2 += __shfl_xor(s2, msk);
  }
  float mean = s * (1.f / 256.f);
  float var = s2 * (1.f / 256.f) - mean * mean;
  float rs = rsqrtf(var + 1e-5f);
  float4 g4 = *(const float4*)(gw + lane * 4);
  float4 b4 = *(const float4*)(gb + lane * 4);
  bf16x4 o;
  o[0] = (bf16_t)((v.x - mean) * rs * g4.x + b4.x);
  o[1] = (bf16_t)((v.y - mean) * rs * g4.y + b4.y);
  o[2] = (bf16_t)((v.z - mean) * rs * g4.z + b4.z);
  o[3] = (bf16_t)((v.w - mean) * rs * g4.w + b4.w);
  *(bf16x4*)(dst + m * 256 + lane * 4) = o;
}

// ---------------- GEMM: C[M,N] = A[M,K] @ Bw[N,K]^T + bias, epilogue variants ----------------
// m97 structure: global_load_lds width-16 staging, linear [128][32] LDS, 2 barriers/K-step.
// Each wave stages 32 rows of A and B per K-step = 2 GLDS issues per tile
// (one issue = 64 lanes x 16B = 16 rows of a 64B-row tile).
// EPI 0: qkv scatter (q/k/v_t layouts)   out_bf = qkv base
// EPI 1: proj + reverse-shift residual   out_f[dst] = val + resid[dst]
// EPI 2: exact gelu -> bf16 [m][1024]
// EPI 3: + resid[m*256+n] -> fp32 out
template <int EPI>
__global__ __launch_bounds__(256) void gemm_kernel(const bf16_t* __restrict__ A,
                                                   const bf16_t* __restrict__ Bw,
                                                   const float* __restrict__ bias, int K,
                                                   bf16_t* __restrict__ out_bf, float* out_f,
                                                   const float* resid) {
  __shared__ __align__(16) bf16_t As[128 * 32];
  __shared__ __align__(16) bf16_t Bs[128 * 32];
  int tid = threadIdx.x;
  int lane = tid & 63, wv = tid >> 6;
  int wm = wv >> 1, wn = wv & 1;
  long m0 = (long)blockIdx.y * 128;
  int n0 = blockIdx.x * 128;
  int lr = lane & 15, lk = (lane >> 4) * 8, g = lane >> 4;

  // staging: lane l covers row (l>>2), col (l&3)*8 of a 16-row slab (1024B);
  // wave wv owns rows [wv*32, wv*32+32) = two slabs per tile.
  const bf16_t* gA0 = A + (m0 + wv * 32 + (lane >> 2)) * K + (lane & 3) * 8;
  const bf16_t* gA1 = gA0 + 16 * K;
  const bf16_t* gB0 = Bw + (long)(n0 + wv * 32 + (lane >> 2)) * K + (lane & 3) * 8;
  const bf16_t* gB1 = gB0 + 16 * K;
  bf16_t* lA = As + wv * 1024;  // wave-uniform LDS base (elements); slab = 512 els
  bf16_t* lB = Bs + wv * 1024;

  f32x4 acc[4][4] = {};
  for (int k0 = 0; k0 < K; k0 += 32) {
    GLDS(gA0 + k0, lA);
    GLDS(gA1 + k0, lA + 512);
    GLDS(gB0 + k0, lB);
    GLDS(gB1 + k0, lB + 512);
    __syncthreads();  // compiler drains vmcnt(0) here -> LDS tile ready
    bf16x8 af[4], bfr[4];
#pragma unroll
    for (int mf = 0; mf < 4; ++mf)
      af[mf] = *(const bf16x8*)(As + (wm * 64 + mf * 16 + lr) * 32 + lk);
#pragma unroll
    for (int nf = 0; nf < 4; ++nf)
      bfr[nf] = *(const bf16x8*)(Bs + (wn * 64 + nf * 16 + lr) * 32 + lk);
#pragma unroll
    for (int mf = 0; mf < 4; ++mf)
#pragma unroll
      for (int nf = 0; nf < 4; ++nf)
        acc[mf][nf] = __builtin_amdgcn_mfma_f32_16x16x32_bf16(af[mf], bfr[nf], acc[mf][nf], 0, 0, 0);
    __syncthreads();  // all waves done reading before next overwrite
  }

#pragma unroll
  for (int mf = 0; mf < 4; ++mf) {
#pragma unroll
    for (int nf = 0; nf < 4; ++nf) {
      long mb = m0 + wm * 64 + mf * 16 + 4 * g;  // 4-aligned row base (r = 0..3 consecutive)
      int n = n0 + wn * 64 + nf * 16 + lr;
      float bn = bias[n];
      if (EPI == 0) {
        long b_ = mb >> 6;
        int tok = (int)(mb & 63);  // 4-aligned, never crosses window boundary
        int which = n >> 8, rem = n & 255, head = rem >> 5, d = rem & 31;
        if (which == 2) {
          bf16x4 o;
#pragma unroll
          for (int r = 0; r < 4; ++r) o[r] = (bf16_t)(acc[mf][nf][r] + bn);
          *(bf16x4*)(out_bf + 2 * QKV_SEG + ((b_ * 8 + head) * 32 + d) * 64 + tok) = o;
        } else {
          long base = (long)which * QKV_SEG + ((b_ * 8 + head) * 64 + tok) * 32 + d;
#pragma unroll
          for (int r = 0; r < 4; ++r) out_bf[base + r * 32] = (bf16_t)(acc[mf][nf][r] + bn);
        }
      } else if (EPI == 1) {
#pragma unroll
        for (int r = 0; r < 4; ++r) {
          long m = mb + r;
          long b_ = m >> 6; int tok = (int)(m & 63);
          int bb = (int)(b_ >> 8), win = (int)(b_ & 255);
          int wh = win >> 4, ww = win & 15;
          int ii = tok >> 3, jj = tok & 7;
          int hh = (wh * 8 + ii + 4) & 127, wp = (ww * 8 + jj + 4) & 127;
          long dst = (((long)bb << 14) + (hh << 7) + wp) * 256 + n;
          out_f[dst] = acc[mf][nf][r] + bn + resid[dst];
        }
      } else if (EPI == 2) {
#pragma unroll
        for (int r = 0; r < 4; ++r) {
          float val = acc[mf][nf][r] + bn;
          float t = 0.5f * val * (1.0f + erff(val * 0.70710678118654752f));
          out_bf[(mb + r) * 1024 + n] = (bf16_t)t;
        }
      } else {
#pragma unroll
        for (int r = 0; r < 4; ++r) {
          long idx = (mb + r) * 256 + n;
          out_f[idx] = acc[mf][nf][r] + bn + resid[idx];
        }
      }
    }
  }
}

// ---------------- per-window attention: 4 waves x 2 heads ----------------
__global__ __launch_bounds__(256) void attn_kernel(const bf16_t* __restrict__ qkv,
                                                   const float* __restrict__ rpb,
                                                   bf16_t* __restrict__ attn_out) {
  __shared__ float rpb_s[1800];       // 225 x 8
  __shared__ bf16_t P[4][64][72];     // +8 pad: 144B stride -> 2-way (free)
  int tid = threadIdx.x, lane = tid & 63, wv = tid >> 6;
  long b_ = blockIdx.x;
  for (int i = tid; i < 1800; i += 256) rpb_s[i] = rpb[i];
  __syncthreads();
  const bf16_t* q = qkv;
  const bf16_t* k = qkv + QKV_SEG;
  const bf16_t* vt = qkv + 2 * QKV_SEG;
  int lr = lane & 15, lk = (lane >> 4) * 8, g = lane >> 4;
  const float scale = 0.17677669529663688f;  // 32^-0.5

  for (int hh = 0; hh < 2; ++hh) {
    int head = wv * 2 + hh;
    long base = (b_ * 8 + head) * 2048;
    bf16x8 af[4], bfr[4];
#pragma unroll
    for (int mf = 0; mf < 4; ++mf)
      af[mf] = *(const bf16x8*)(q + base + (mf * 16 + lr) * 32 + lk);
#pragma unroll
    for (int nf = 0; nf < 4; ++nf)
      bfr[nf] = *(const bf16x8*)(k + base + (nf * 16 + lr) * 32 + lk);
    f32x4 S[4][4] = {};
#pragma unroll
    for (int mf = 0; mf < 4; ++mf)
#pragma unroll
      for (int nf = 0; nf < 4; ++nf)
        S[mf][nf] = __builtin_amdgcn_mfma_f32_16x16x32_bf16(af[mf], bfr[nf], S[mf][nf], 0, 0, 0);
    // scale + relative position bias
#pragma unroll
    for (int mf = 0; mf < 4; ++mf)
#pragma unroll
      for (int nf = 0; nf < 4; ++nf)
#pragma unroll
        for (int r = 0; r < 4; ++r) {
          int i = mf * 16 + 4 * g + r, j = nf * 16 + lr;
          int rel = ((i >> 3) - (j >> 3) + 7) * 15 + ((i & 7) - (j & 7) + 7);
          S[mf][nf][r] = S[mf][nf][r] * scale + rpb_s[rel * 8 + head];
        }
    // softmax over rows (16-lane groups hold a row's 64 cols as 4 frags x 16 lanes)
#pragma unroll
    for (int mf = 0; mf < 4; ++mf) {
#pragma unroll
      for (int r = 0; r < 4; ++r) {
        float mx = fmaxf(fmaxf(S[mf][0][r], S[mf][1][r]), fmaxf(S[mf][2][r], S[mf][3][r]));
#pragma unroll
        for (int msk = 1; msk < 16; msk <<= 1) mx = fmaxf(mx, __shfl_xor(mx, msk));
        float sm = 0.f;
#pragma unroll
        for (int nf = 0; nf < 4; ++nf) {
          float e = __expf(S[mf][nf][r] - mx);
          S[mf][nf][r] = e;
          sm += e;
        }
#pragma unroll
        for (int msk = 1; msk < 16; msk <<= 1) sm += __shfl_xor(sm, msk);
        float is = 1.f / sm;
        int i = mf * 16 + 4 * g + r;
#pragma unroll
        for (int nf = 0; nf < 4; ++nf) P[wv][i][nf * 16 + lr] = (bf16_t)(S[mf][nf][r] * is);
      }
    }
    // O = P @ V   (A from LDS P, B from transposed v_t, contiguous)
    f32x4 O[4][2] = {};
#pragma unroll
    for (int ks = 0; ks < 2; ++ks) {
      int j0 = ks * 32;
      bf16x8 pa[4], vb[2];
#pragma unroll
      for (int mf = 0; mf < 4; ++mf) pa[mf] = *(const bf16x8*)(&P[wv][mf * 16 + lr][j0 + lk]);
#pragma unroll
      for (int nf = 0; nf < 2; ++nf)
        vb[nf] = *(const bf16x8*)(vt + base + (nf * 16 + lr) * 64 + j0 + lk);
#pragma unroll
      for (int mf = 0; mf < 4; ++mf)
#pragma unroll
        for (int nf = 0; nf < 2; ++nf)
          O[mf][nf] = __builtin_amdgcn_mfma_f32_16x16x32_bf16(pa[mf], vb[nf], O[mf][nf], 0, 0, 0);
    }
#pragma unroll
    for (int mf = 0; mf < 4; ++mf)
#pragma unroll
      for (int nf = 0; nf < 2; ++nf)
#pragma unroll
        for (int r = 0; r < 4; ++r) {
          int i = mf * 16 + 4 * g + r, d = nf * 16 + lr;
          attn_out[(b_ * 64 + i) * 256 + head * 32 + d] = (bf16_t)O[mf][nf][r];
        }
  }
}

extern "C" void kernel_launch(void* const* d_in, const int* in_sizes, int n_in,
                              void* d_out, int out_size, void* d_ws, size_t ws_size,
                              hipStream_t stream) {
  const float* x = (const float*)d_in[0];
  const float* n1w = (const float*)d_in[1];
  const float* n1b = (const float*)d_in[2];
  const float* qkv_w = (const float*)d_in[3];
  const float* qkv_b = (const float*)d_in[4];
  const float* rpb = (const float*)d_in[5];
  const float* proj_w = (const float*)d_in[6];
  const float* proj_b = (const float*)d_in[7];
  const float* n2w = (const float*)d_in[8];
  const float* n2b = (const float*)d_in[9];
  const float* fc1_w = (const float*)d_in[10];
  const float* fc1_b = (const float*)d_in[11];
  const float* fc2_w = (const float*)d_in[12];
  const float* fc2_b = (const float*)d_in[13];
  float* out = (float*)d_out;

  char* ws = (char*)d_ws;
  bf16_t* bufA = (bf16_t*)ws;                       // qkv (201MB) then h (268MB)
  bf16_t* bufB = (bf16_t*)(ws + 268435456L);        // xw / attn_out / y (67MB)
  bf16_t* wq = (bf16_t*)(ws + 335544320L);          // bf16 weights (1.6MB)
  bf16_t* wp = wq + 196608;
  bf16_t* w1 = wp + 65536;
  bf16_t* w2 = w1 + 262144;

  // weights -> bf16
  cvt_kernel<<<192, 256, 0, stream>>>(qkv_w, wq);
  cvt_kernel<<<64, 256, 0, stream>>>(proj_w, wp);
  cvt_kernel<<<256, 256, 0, stream>>>(fc1_w, w1);
  cvt_kernel<<<256, 256, 0, stream>>>(fc2_w, w2);

  // LN1 + shift + window partition -> xw (bufB)
  ln_kernel<<<32768, 256, 0, stream>>>(x, n1w, n1b, bufB, 1);
  // QKV GEMM -> q/k/v_t (bufA)
  gemm_kernel<0><<<dim3(6, 1024), 256, 0, stream>>>(bufB, wq, qkv_b, 256, bufA, nullptr, nullptr);
  // window attention -> attn_out (bufB)
  attn_kernel<<<2048, 256, 0, stream>>>(bufA, rpb, bufB);
  // proj + reverse shift + residual -> x1 (d_out, fp32)
  gemm_kernel<1><<<dim3(2, 1024), 256, 0, stream>>>(bufB, wp, proj_b, 256, nullptr, out, x);
  // LN2 -> y (bufB)
  ln_kernel<<<32768, 256, 0, stream>>>(out, n2w, n2b, bufB, 0);
  // FC1 + gelu -> h (bufA)
  gemm_kernel<2><<<dim3(8, 1024), 256, 0, stream>>>(bufB, w1, fc1_b, 256, bufA, nullptr, nullptr);
  // FC2 + residual -> out (in-place x1 + y)
  gemm_kernel<3><<<dim3(2, 1024), 256, 0, stream>>>(bufA, w2, fc2_b, 1024, nullptr, out, out);
}